// Round 18
// baseline (306.895 us; speedup 1.0000x reference)
//
#include <hip/hip_runtime.h>
#include <hip/hip_bf16.h>
#include <hip/hip_fp16.h>

#define N_NODES 50000
#define N_EDGES 1600000
#define IN_CH 256
#define NEG_SLOPE 0.2f
#define EPS_F 1e-16f
#define CNT_PAD 16      // one 64B line per counter (agg kernels read cnt[n*16])
#define CAP 128         // bucket capacity per node (Poisson(32): P(>=128) ~ 1e-37)
#define NBK 196         // coarse buckets: dst>>8, 50000/256 -> 0..195
#define CAPB 10240      // coarse bucket capacity (mean 8163, +23 sigma)
#define PCHUNK 3125     // edges per k_part block (512 * 3125 = 1.6M)
#define KTILE 64                 // 17.4KB xs + 32KB w1s -> 3 blocks/CU
#define XS_PITCH (KTILE + 4)

__device__ __forceinline__ float lrelu(float x) {
    return x > 0.f ? x : NEG_SLOPE * x;
}

__device__ __forceinline__ float2 h2f(unsigned int w) {
    __half2 h;
    *reinterpret_cast<unsigned int*>(&h) = w;
    return __half22float2(h);
}

__device__ __forceinline__ unsigned int f2h2(float a, float b) {
    __half2 h = __floats2half2_rn(a, b);
    return *reinterpret_cast<unsigned int*>(&h);
}

// -------- Kernel 0a: detect edge_index storage; zero gcnt --------
__global__ __launch_bounds__(256) void k0_detect(const int* __restrict__ ei,
                                                 int* __restrict__ flag,
                                                 int* __restrict__ gcnt)
{
    __shared__ int nz;
    const int t = threadIdx.x;
    if (t == 0) nz = 0;
    if (t < 256) gcnt[t] = 0;
    __syncthreads();
    if (t & 1) { if (ei[t] != 0) atomicAdd(&nz, 1); }
    __syncthreads();
    if (t == 0) flag[0] = (nz == 0) ? 1 : 0;   // 1 => int64 layout
}

__device__ __forceinline__ int ld_src(const int* ei, int f, int e) {
    return f ? ei[2 * (size_t)e] : ei[e];
}
__device__ __forceinline__ int ld_dst(const int* ei, int f, int e) {
    return f ? ei[2 * (size_t)N_EDGES + 2 * (size_t)e]
             : ei[(size_t)N_EDGES + e];
}

// -------- Build pass 1: coarse partition by dst>>8 (LDS hist + cursors) --------
__global__ __launch_bounds__(1024) void k_part(const int* __restrict__ ei,
                                               const int* __restrict__ flag,
                                               int* __restrict__ gcnt,
                                               int2* __restrict__ bseg)
{
    __shared__ int hist[NBK];
    __shared__ int cur[NBK];
    const int t = threadIdx.x;
    for (int j = t; j < NBK; j += 1024) hist[j] = 0;
    __syncthreads();
    const int f = flag[0];
    const int e0 = blockIdx.x * PCHUNK;
    const int e1 = min(e0 + PCHUNK, N_EDGES);
    for (int e = e0 + t; e < e1; e += 1024)
        atomicAdd(&hist[ld_dst(ei, f, e) >> 8], 1);
    __syncthreads();
    for (int j = t; j < NBK; j += 1024)
        cur[j] = j * CAPB + atomicAdd(&gcnt[j], hist[j]);
    __syncthreads();
    for (int e = e0 + t; e < e1; e += 1024) {
        const int s = ld_src(ei, f, e);
        const int d = ld_dst(ei, f, e);
        const int bk = d >> 8;
        const int pos = atomicAdd(&cur[bk], 1);
        if (pos - bk * CAPB < CAPB) bseg[pos] = make_int2(s, d);
    }
}

// -------- Build pass 2: per-bucket fine scatter into fixed-stride CSR --------
__global__ __launch_bounds__(1024) void k_sub(const int* __restrict__ gcnt,
                                              const int2* __restrict__ bseg,
                                              int* __restrict__ cnt,
                                              int* __restrict__ csr_src)
{
    __shared__ int cur[256];
    const int b = blockIdx.x;
    const int t = threadIdx.x;
    if (t < 256) cur[t] = 0;
    __syncthreads();
    const int count = min(gcnt[b], CAPB);
    const int2* seg = bseg + (size_t)b * CAPB;
    for (int i = t; i < count; i += 1024) {
        const int2 e = seg[i];
        const int slot = atomicAdd(&cur[e.y & 255], 1);
        if (slot < CAP) csr_src[((size_t)e.y << 7) + slot] = e.x;
    }
    __syncthreads();
    if (t < 256) {
        const int n = b * 256 + t;
        if (n < N_NODES) cnt[(size_t)n * CNT_PAD] = min(cur[t], CAP);
    }
}

// ---------------- Kernel 1: h1 = x @ W1 (fp16 out) ; a_src1/a_dst1 fused ----------------
// Register-blocked 2 rows x 4 cols; KTILE=64 for 3 blocks/CU occupancy.
__global__ __launch_bounds__(256) void k1_gemm1(
    const float* __restrict__ x, const float* __restrict__ W1,
    const float* __restrict__ att_src1, const float* __restrict__ att_dst1,
    __half* __restrict__ h1, float* __restrict__ a_src1, float* __restrict__ a_dst1)
{
    __shared__ float w1s[IN_CH * 32];        // full K, [k][col]  (32 KB)
    __shared__ float xs[64 * XS_PITCH];      // K-tile of 64      (17.4 KB)
    __shared__ float attss[32], attds[32];
    const int t = threadIdx.x;
    for (int i = t; i < IN_CH * 32; i += 256) w1s[i] = W1[i];
    if (t < 32) { attss[t] = att_src1[t]; attds[t] = att_dst1[t]; }
    const int row0 = blockIdx.x * 64;
    const int colq = t & 7, c4 = colq * 4;
    const int rp = t >> 3;
    const int r0 = rp * 2, r1 = r0 + 1;
    float4 a0 = make_float4(0.f, 0.f, 0.f, 0.f);
    float4 a1 = make_float4(0.f, 0.f, 0.f, 0.f);
    for (int kb = 0; kb < IN_CH; kb += KTILE) {
        __syncthreads();
        #pragma unroll
        for (int i = 0; i < 4; ++i) {        // 64 rows x 16 float4
            const int idx = t + 256 * i;
            const int r = idx >> 4, p = idx & 15;
            const int row = row0 + r;
            float4 vv = make_float4(0.f, 0.f, 0.f, 0.f);
            if (row < N_NODES)
                vv = *(const float4*)(x + (size_t)row * IN_CH + kb + p * 4);
            *(float4*)(&xs[r * XS_PITCH + p * 4]) = vv;
        }
        __syncthreads();
        #pragma unroll 8
        for (int kt = 0; kt < KTILE; ++kt) {
            const float xv0 = xs[r0 * XS_PITCH + kt];
            const float xv1 = xs[r1 * XS_PITCH + kt];
            const float4 wv = *(const float4*)(&w1s[(kb + kt) * 32 + c4]);
            a0.x += xv0 * wv.x; a0.y += xv0 * wv.y;
            a0.z += xv0 * wv.z; a0.w += xv0 * wv.w;
            a1.x += xv1 * wv.x; a1.y += xv1 * wv.y;
            a1.z += xv1 * wv.z; a1.w += xv1 * wv.w;
        }
    }
    const int row_a = row0 + r0, row_b = row0 + r1;
    if (row_a < N_NODES) {
        uint2 p; p.x = f2h2(a0.x, a0.y); p.y = f2h2(a0.z, a0.w);
        *(uint2*)(h1 + (size_t)row_a * 32 + c4) = p;
    }
    if (row_b < N_NODES) {
        uint2 p; p.x = f2h2(a1.x, a1.y); p.y = f2h2(a1.z, a1.w);
        *(uint2*)(h1 + (size_t)row_b * 32 + c4) = p;
    }
    float sa0 = a0.x * attss[c4] + a0.y * attss[c4 + 1]
              + a0.z * attss[c4 + 2] + a0.w * attss[c4 + 3];
    float sd0 = a0.x * attds[c4] + a0.y * attds[c4 + 1]
              + a0.z * attds[c4 + 2] + a0.w * attds[c4 + 3];
    float sa1 = a1.x * attss[c4] + a1.y * attss[c4 + 1]
              + a1.z * attss[c4 + 2] + a1.w * attss[c4 + 3];
    float sd1 = a1.x * attds[c4] + a1.y * attds[c4 + 1]
              + a1.z * attds[c4 + 2] + a1.w * attds[c4 + 3];
    sa0 += __shfl_xor(sa0, 1); sa0 += __shfl_xor(sa0, 2);
    sd0 += __shfl_xor(sd0, 1); sd0 += __shfl_xor(sd0, 2);
    sa1 += __shfl_xor(sa1, 1); sa1 += __shfl_xor(sa1, 2);
    sd1 += __shfl_xor(sd1, 1); sd1 += __shfl_xor(sd1, 2);
    const int head = colq >> 2;
    if ((colq & 3) == 0) {
        if (row_a < N_NODES) {
            a_src1[row_a * 2 + head] = sa0;
            a_dst1[row_a * 2 + head] = sd0;
        }
        if (row_b < N_NODES) {
            a_src1[row_b * 2 + head] = sa1;
            a_dst1[row_b * 2 + head] = sd1;
        }
    }
}

// -------- k_wgt1: per-(edge,head) softmax weights, computed ONCE --------
// Bit-identical arithmetic to the old in-agg computation (fp32 storage).
__global__ __launch_bounds__(256) void k_wgt1(
    const int* __restrict__ cnt, const int* __restrict__ csr_src,
    const float* __restrict__ a_src1, const float* __restrict__ a_dst1,
    float2* __restrict__ wgt1)
{
    const int idx = blockIdx.x * 256 + threadIdx.x;   // node*128 + slot
    const int n = idx >> 7, slot = idx & 127;
    if (n >= N_NODES) return;
    if (slot >= cnt[(size_t)n * CNT_PAD]) return;
    const int s = csr_src[idx];
    const float2 as = *(const float2*)(a_src1 + 2 * (size_t)s);
    const float2 ad = *(const float2*)(a_dst1 + 2 * (size_t)n);
    wgt1[idx] = make_float2(__expf(lrelu(as.x + ad.x)),
                            __expf(lrelu(as.y + ad.y)));
}

// -------- Layer-1 aggregation: precomputed weights, 8-way unroll --------
__global__ __launch_bounds__(256) void k_agg1(
    const int* __restrict__ cnt, const int* __restrict__ csr_src,
    const float* __restrict__ wgtf,   // wgt1 viewed as float[slot*2+head]
    const __half* __restrict__ h1, float* __restrict__ out1)
{
    const int wid = (blockIdx.x * 256 + threadIdx.x) >> 6;
    const int lane = threadIdx.x & 63;
    if (wid >= N_NODES) return;
    const int len = min(cnt[(size_t)wid * CNT_PAD], CAP);
    const int beg = wid << 7, end = beg + len;
    const int slot = lane >> 5, ch = lane & 31;
    const int head = ch >> 4;
    const int rep = ((ch & 15) == 0);
    float acc = 0.f, sw = 0.f;
    int i = beg + slot;
    for (; i + 14 < end; i += 16) {
        int s[8]; float w[8], h[8];
        #pragma unroll
        for (int j = 0; j < 8; ++j) s[j] = csr_src[i + 2 * j];
        #pragma unroll
        for (int j = 0; j < 8; ++j) w[j] = wgtf[2 * (size_t)(i + 2 * j) + head];
        #pragma unroll
        for (int j = 0; j < 8; ++j) h[j] = __half2float(h1[(size_t)s[j] * 32 + ch]);
        float wsum = 0.f;
        #pragma unroll
        for (int j = 0; j < 8; ++j) { wsum += w[j]; acc += w[j] * h[j]; }
        if (rep) sw += wsum;
    }
    for (; i < end; i += 2) {
        const int s = csr_src[i];
        const float w = wgtf[2 * (size_t)i + head];
        if (rep) sw += w;
        acc += w * __half2float(h1[(size_t)s * 32 + ch]);
    }
    sw += __shfl_xor(sw, 32);
    const float swh = __shfl(sw, head << 4);
    acc += __shfl_xor(acc, 32);
    const float inv = 1.f / (swh + EPS_F);
    if (lane < 32) out1[(size_t)wid * 32 + lane] = acc * inv;
}

// ---------------- Kernel 4: h2 = elu(out1+b1) @ W2 ; a_src2/a_dst2 fused ----------------
__global__ __launch_bounds__(256) void k4_layer2(
    const float* __restrict__ out1, const float* __restrict__ b1,
    const float* __restrict__ W2, const float* __restrict__ att_src2,
    const float* __restrict__ att_dst2,
    float* __restrict__ h2, float* __restrict__ a_src2, float* __restrict__ a_dst2)
{
    __shared__ float act[16][32];
    __shared__ float w2s[32 * 16];
    __shared__ float b1s[32], as2[16], ad2[16];
    const int t = threadIdx.x;
    for (int i = t; i < 512; i += 256) w2s[i] = W2[i];
    if (t < 32) b1s[t] = b1[t];
    if (t < 16) { as2[t] = att_src2[t]; ad2[t] = att_dst2[t]; }
    __syncthreads();
    const int node0 = blockIdx.x * 16;
    for (int i = t; i < 512; i += 256) {
        const int nl = i >> 5, k = i & 31;
        const int row = node0 + nl;
        float v = 0.f;
        if (row < N_NODES) {
            v = out1[(size_t)row * 32 + k] + b1s[k];
            v = v > 0.f ? v : expm1f(v);
        }
        act[nl][k] = v;
    }
    __syncthreads();
    const int nl = t >> 4, j = t & 15;
    const int row = node0 + nl;
    float acc = 0.f;
    #pragma unroll
    for (int k = 0; k < 32; ++k) acc += act[nl][k] * w2s[k * 16 + j];
    if (row < N_NODES) h2[(size_t)row * 16 + j] = acc;
    float sa = acc * as2[j], sd = acc * ad2[j];
    #pragma unroll
    for (int m = 1; m < 16; m <<= 1) { sa += __shfl_xor(sa, m); sd += __shfl_xor(sd, m); }
    if (j == 0 && row < N_NODES) { a_src2[row] = sa; a_dst2[row] = sd; }
}

// -------- k_wgt2: layer-2 per-edge softmax weights --------
__global__ __launch_bounds__(256) void k_wgt2(
    const int* __restrict__ cnt, const int* __restrict__ csr_src,
    const float* __restrict__ a_src2, const float* __restrict__ a_dst2,
    float* __restrict__ wgt2)
{
    const int idx = blockIdx.x * 256 + threadIdx.x;
    const int n = idx >> 7, slot = idx & 127;
    if (n >= N_NODES) return;
    if (slot >= cnt[(size_t)n * CNT_PAD]) return;
    const int s = csr_src[idx];
    wgt2[idx] = __expf(lrelu(a_src2[s] + a_dst2[n]));
}

// -------- Layer-2 aggregation: precomputed weights, 8-way unroll --------
__global__ __launch_bounds__(256) void k_agg2(
    const int* __restrict__ cnt, const int* __restrict__ csr_src,
    const float* __restrict__ wgt2,
    const float* __restrict__ h2, float* __restrict__ out2)
{
    const int wid = (blockIdx.x * 256 + threadIdx.x) >> 6;
    const int lane = threadIdx.x & 63;
    if (wid >= N_NODES) return;
    const int len = min(cnt[(size_t)wid * CNT_PAD], CAP);
    const int beg = wid << 7, end = beg + len;
    const int slot = lane >> 4, ch = lane & 15;
    const int rep = (ch == 0);
    float acc = 0.f, sw = 0.f;
    int i = beg + slot;
    for (; i + 28 < end; i += 32) {
        int s[8]; float w[8], h[8];
        #pragma unroll
        for (int j = 0; j < 8; ++j) s[j] = csr_src[i + 4 * j];
        #pragma unroll
        for (int j = 0; j < 8; ++j) w[j] = wgt2[i + 4 * j];
        #pragma unroll
        for (int j = 0; j < 8; ++j) h[j] = h2[(size_t)s[j] * 16 + ch];
        float wsum = 0.f;
        #pragma unroll
        for (int j = 0; j < 8; ++j) { wsum += w[j]; acc += w[j] * h[j]; }
        if (rep) sw += wsum;
    }
    for (; i < end; i += 4) {
        const int s = csr_src[i];
        const float w = wgt2[i];
        if (rep) sw += w;
        acc += w * h2[(size_t)s * 16 + ch];
    }
    #pragma unroll
    for (int m = 1; m < 64; m <<= 1) sw += __shfl_xor(sw, m);
    acc += __shfl_xor(acc, 16);
    acc += __shfl_xor(acc, 32);
    const float inv = 1.f / (sw + EPS_F);
    if (lane < 16) out2[(size_t)wid * 16 + lane] = acc * inv;
}

// -------- k_prep: hoist edge-MLP first layer to nodes (fp16 u/v) --------
__global__ __launch_bounds__(256) void k_prep(
    const float* __restrict__ out2, const float* __restrict__ b2,
    const float* __restrict__ Wm1, const float* __restrict__ bm1,
    __half* __restrict__ u, __half* __restrict__ v)
{
    __shared__ float wa[16 * 16], wb[16 * 16];
    __shared__ float act[16][17];
    __shared__ float b2s[16], bm1s[16];
    const int t = threadIdx.x;
    if (t < 256) {
        const int k = t >> 4, j = t & 15;
        wa[t] = Wm1[k * 16 + j];
        wb[t] = Wm1[(16 + k) * 16 + j];
    }
    if (t < 16) { b2s[t] = b2[t]; bm1s[t] = bm1[t]; }
    __syncthreads();
    const int node0 = blockIdx.x * 16;
    const int nl = t >> 4, c = t & 15;
    const int row = node0 + nl;
    act[nl][c] = (row < N_NODES) ? out2[(size_t)row * 16 + c] + b2s[c] : 0.f;
    __syncthreads();
    float su = bm1s[c], sv = 0.f;
    #pragma unroll
    for (int k = 0; k < 16; ++k) {
        const float a = act[nl][k];
        su += a * wa[k * 16 + c];
        sv += a * wb[k * 16 + c];
    }
    if (row < N_NODES) {
        u[(size_t)row * 16 + c] = __float2half(su);
        v[(size_t)row * 16 + c] = __float2half(sv);
    }
}

// ---------------- Kernel 7 lite: per-edge tail of the MLP (fp16 gathers) ----------------
__global__ __launch_bounds__(256) void k7_lite(
    const int* __restrict__ ei, const int* __restrict__ flag,
    const __half* __restrict__ u, const __half* __restrict__ v,
    const float* __restrict__ Wm2, const float* __restrict__ bm2,
    float* __restrict__ out)
{
    __shared__ float wm2s[16];
    __shared__ float bm2s;
    const int t = threadIdx.x;
    if (t < 16) wm2s[t] = Wm2[t];
    if (t == 0) bm2s = bm2[0];
    __syncthreads();
    const int e = blockIdx.x * 256 + t;
    if (e >= N_EDGES) return;
    const int f = flag[0];
    const int s = ld_src(ei, f, e);
    const int d = ld_dst(ei, f, e);
    const uint4* up = (const uint4*)(u + (size_t)s * 16);
    const uint4* vp = (const uint4*)(v + (size_t)d * 16);
    const uint4 ua = up[0], ub = up[1];
    const uint4 va = vp[0], vb = vp[1];
    float fl = bm2s;
    unsigned int uw[8] = {ua.x, ua.y, ua.z, ua.w, ub.x, ub.y, ub.z, ub.w};
    unsigned int vw[8] = {va.x, va.y, va.z, va.w, vb.x, vb.y, vb.z, vb.w};
    #pragma unroll
    for (int i = 0; i < 8; ++i) {
        const float2 a = h2f(uw[i]);
        const float2 b = h2f(vw[i]);
        fl += fmaxf(a.x + b.x, 0.f) * wm2s[2 * i];
        fl += fmaxf(a.y + b.y, 0.f) * wm2s[2 * i + 1];
    }
    out[e] = fmaxf(fl, 0.f);
}

extern "C" void kernel_launch(void* const* d_in, const int* in_sizes, int n_in,
                              void* d_out, int out_size, void* d_ws, size_t ws_size,
                              hipStream_t stream)
{
    const float* x        = (const float*)d_in[0];
    const int*   ei       = (const int*)d_in[1];
    const float* W1       = (const float*)d_in[2];
    const float* att_src1 = (const float*)d_in[3];
    const float* att_dst1 = (const float*)d_in[4];
    const float* b1       = (const float*)d_in[5];
    const float* W2       = (const float*)d_in[6];
    const float* att_src2 = (const float*)d_in[7];
    const float* att_dst2 = (const float*)d_in[8];
    const float* b2       = (const float*)d_in[9];
    const float* Wm1      = (const float*)d_in[10];
    const float* bm1      = (const float*)d_in[11];
    const float* Wm2      = (const float*)d_in[12];
    const float* bm2      = (const float*)d_in[13];

    float* ws = (float*)d_ws;
    size_t off = 0;
    __half* h1 = (__half*)(ws + off); off += 16 * (size_t)N_NODES;
    float* a_src1 = ws + off; off += 2  * (size_t)N_NODES;
    float* a_dst1 = ws + off; off += 2  * (size_t)N_NODES;
    float* out1   = ws + off; off += 32 * (size_t)N_NODES;
    float* h2     = ws + off; off += 16 * (size_t)N_NODES;
    float* a_src2 = ws + off; off += 1  * (size_t)N_NODES;
    float* a_dst2 = ws + off; off += 1  * (size_t)N_NODES;
    float* out2   = ws + off; off += 16 * (size_t)N_NODES;
    __half* u = (__half*)(ws + off); off += 8 * (size_t)N_NODES;
    __half* v = (__half*)(ws + off); off += 8 * (size_t)N_NODES;
    int* cnt     = (int*)(ws + off); off += (size_t)N_NODES * CNT_PAD;
    int* csr_src = (int*)(ws + off); off += (size_t)N_NODES * CAP;
    float2* wgt1 = (float2*)(ws + off); off += 2 * (size_t)N_NODES * CAP;  // 51.2 MB
    float* wgt2  = ws + off; off += (size_t)N_NODES * CAP;                 // 25.6 MB
    int* gcnt    = (int*)(ws + off); off += 256;
    int* flag    = (int*)(ws + off); off += 64;
    // bseg (16.06 MB) overlays the h1..out2 region: dead before k1_gemm1 runs.
    int2* bseg = (int2*)ws;

    k0_detect<<<1, 256, 0, stream>>>(ei, flag, gcnt);
    k_part<<<(N_EDGES + PCHUNK - 1) / PCHUNK, 1024, 0, stream>>>(ei, flag, gcnt, bseg);
    k_sub<<<NBK, 1024, 0, stream>>>(gcnt, bseg, cnt, csr_src);

    k1_gemm1<<<(N_NODES + 63) / 64, 256, 0, stream>>>(
        x, W1, att_src1, att_dst1, h1, a_src1, a_dst1);
    k_wgt1<<<(N_NODES * CAP + 255) / 256, 256, 0, stream>>>(
        cnt, csr_src, a_src1, a_dst1, wgt1);
    k_agg1<<<(N_NODES + 3) / 4, 256, 0, stream>>>(
        cnt, csr_src, (const float*)wgt1, h1, out1);
    k4_layer2<<<(N_NODES + 15) / 16, 256, 0, stream>>>(
        out1, b1, W2, att_src2, att_dst2, h2, a_src2, a_dst2);
    k_wgt2<<<(N_NODES * CAP + 255) / 256, 256, 0, stream>>>(
        cnt, csr_src, a_src2, a_dst2, wgt2);
    k_agg2<<<(N_NODES + 3) / 4, 256, 0, stream>>>(
        cnt, csr_src, wgt2, h2, out2);
    k_prep<<<(N_NODES + 15) / 16, 256, 0, stream>>>(
        out2, b2, Wm1, bm1, u, v);
    k7_lite<<<(N_EDGES + 255) / 256, 256, 0, stream>>>(
        ei, flag, u, v, Wm2, bm2, (float*)d_out);
}

// Round 19
// 276.863 us; speedup vs baseline: 1.1085x; 1.1085x over previous
//
#include <hip/hip_runtime.h>
#include <hip/hip_bf16.h>
#include <hip/hip_fp16.h>

#define N_NODES 50000
#define N_EDGES 1600000
#define IN_CH 256
#define NEG_SLOPE 0.2f
#define EPS_F 1e-16f
#define CNT_PAD 16      // one 64B line per counter (agg kernels read cnt[n*16])
#define CAP 128         // bucket capacity per node (Poisson(32): P(>=128) ~ 1e-37)
#define NBK 196         // coarse buckets: dst>>8, 50000/256 -> 0..195
#define CAPB 10240      // coarse bucket capacity (mean 8163, +23 sigma)
#define PCHUNK 3125     // edges per k_part block (512 * 3125 = 1.6M)
#define KTILE 64                 // 17.4KB xs + 32KB w1s -> 3 blocks/CU
#define XS_PITCH (KTILE + 4)

__device__ __forceinline__ float lrelu(float x) {
    return x > 0.f ? x : NEG_SLOPE * x;
}

__device__ __forceinline__ float2 h2f(unsigned int w) {
    __half2 h;
    *reinterpret_cast<unsigned int*>(&h) = w;
    return __half22float2(h);
}

__device__ __forceinline__ unsigned int f2h2(float a, float b) {
    __half2 h = __floats2half2_rn(a, b);
    return *reinterpret_cast<unsigned int*>(&h);
}

// -------- Kernel 0a: detect edge_index storage; zero gcnt --------
__global__ __launch_bounds__(256) void k0_detect(const int* __restrict__ ei,
                                                 int* __restrict__ flag,
                                                 int* __restrict__ gcnt)
{
    __shared__ int nz;
    const int t = threadIdx.x;
    if (t == 0) nz = 0;
    if (t < 256) gcnt[t] = 0;
    __syncthreads();
    if (t & 1) { if (ei[t] != 0) atomicAdd(&nz, 1); }
    __syncthreads();
    if (t == 0) flag[0] = (nz == 0) ? 1 : 0;   // 1 => int64 layout
}

__device__ __forceinline__ int ld_src(const int* ei, int f, int e) {
    return f ? ei[2 * (size_t)e] : ei[e];
}
__device__ __forceinline__ int ld_dst(const int* ei, int f, int e) {
    return f ? ei[2 * (size_t)N_EDGES + 2 * (size_t)e]
             : ei[(size_t)N_EDGES + e];
}

// -------- Build pass 1: coarse partition by dst>>8 (LDS hist + cursors) --------
__global__ __launch_bounds__(1024) void k_part(const int* __restrict__ ei,
                                               const int* __restrict__ flag,
                                               int* __restrict__ gcnt,
                                               int2* __restrict__ bseg)
{
    __shared__ int hist[NBK];
    __shared__ int cur[NBK];
    const int t = threadIdx.x;
    for (int j = t; j < NBK; j += 1024) hist[j] = 0;
    __syncthreads();
    const int f = flag[0];
    const int e0 = blockIdx.x * PCHUNK;
    const int e1 = min(e0 + PCHUNK, N_EDGES);
    for (int e = e0 + t; e < e1; e += 1024)
        atomicAdd(&hist[ld_dst(ei, f, e) >> 8], 1);
    __syncthreads();
    for (int j = t; j < NBK; j += 1024)
        cur[j] = j * CAPB + atomicAdd(&gcnt[j], hist[j]);
    __syncthreads();
    for (int e = e0 + t; e < e1; e += 1024) {
        const int s = ld_src(ei, f, e);
        const int d = ld_dst(ei, f, e);
        const int bk = d >> 8;
        const int pos = atomicAdd(&cur[bk], 1);
        if (pos - bk * CAPB < CAPB) bseg[pos] = make_int2(s, d);
    }
}

// -------- Build pass 2: per-bucket fine scatter into fixed-stride CSR --------
__global__ __launch_bounds__(1024) void k_sub(const int* __restrict__ gcnt,
                                              const int2* __restrict__ bseg,
                                              int* __restrict__ cnt,
                                              int* __restrict__ csr_src)
{
    __shared__ int cur[256];
    const int b = blockIdx.x;
    const int t = threadIdx.x;
    if (t < 256) cur[t] = 0;
    __syncthreads();
    const int count = min(gcnt[b], CAPB);
    const int2* seg = bseg + (size_t)b * CAPB;
    for (int i = t; i < count; i += 1024) {
        const int2 e = seg[i];
        const int slot = atomicAdd(&cur[e.y & 255], 1);
        if (slot < CAP) csr_src[((size_t)e.y << 7) + slot] = e.x;
    }
    __syncthreads();
    if (t < 256) {
        const int n = b * 256 + t;
        if (n < N_NODES) cnt[(size_t)n * CNT_PAD] = min(cur[t], CAP);
    }
}

// ---------------- Kernel 1: h1 = x @ W1 (fp16 out) ; a_src1/a_dst1 fused ----------------
// Register-blocked 2 rows x 4 cols; KTILE=64 for 3 blocks/CU occupancy.
__global__ __launch_bounds__(256) void k1_gemm1(
    const float* __restrict__ x, const float* __restrict__ W1,
    const float* __restrict__ att_src1, const float* __restrict__ att_dst1,
    __half* __restrict__ h1, float* __restrict__ a_src1, float* __restrict__ a_dst1)
{
    __shared__ float w1s[IN_CH * 32];        // full K, [k][col]  (32 KB)
    __shared__ float xs[64 * XS_PITCH];      // K-tile of 64      (17.4 KB)
    __shared__ float attss[32], attds[32];
    const int t = threadIdx.x;
    for (int i = t; i < IN_CH * 32; i += 256) w1s[i] = W1[i];
    if (t < 32) { attss[t] = att_src1[t]; attds[t] = att_dst1[t]; }
    const int row0 = blockIdx.x * 64;
    const int colq = t & 7, c4 = colq * 4;
    const int rp = t >> 3;
    const int r0 = rp * 2, r1 = r0 + 1;
    float4 a0 = make_float4(0.f, 0.f, 0.f, 0.f);
    float4 a1 = make_float4(0.f, 0.f, 0.f, 0.f);
    for (int kb = 0; kb < IN_CH; kb += KTILE) {
        __syncthreads();
        #pragma unroll
        for (int i = 0; i < 4; ++i) {        // 64 rows x 16 float4
            const int idx = t + 256 * i;
            const int r = idx >> 4, p = idx & 15;
            const int row = row0 + r;
            float4 vv = make_float4(0.f, 0.f, 0.f, 0.f);
            if (row < N_NODES)
                vv = *(const float4*)(x + (size_t)row * IN_CH + kb + p * 4);
            *(float4*)(&xs[r * XS_PITCH + p * 4]) = vv;
        }
        __syncthreads();
        #pragma unroll 8
        for (int kt = 0; kt < KTILE; ++kt) {
            const float xv0 = xs[r0 * XS_PITCH + kt];
            const float xv1 = xs[r1 * XS_PITCH + kt];
            const float4 wv = *(const float4*)(&w1s[(kb + kt) * 32 + c4]);
            a0.x += xv0 * wv.x; a0.y += xv0 * wv.y;
            a0.z += xv0 * wv.z; a0.w += xv0 * wv.w;
            a1.x += xv1 * wv.x; a1.y += xv1 * wv.y;
            a1.z += xv1 * wv.z; a1.w += xv1 * wv.w;
        }
    }
    const int row_a = row0 + r0, row_b = row0 + r1;
    if (row_a < N_NODES) {
        uint2 p; p.x = f2h2(a0.x, a0.y); p.y = f2h2(a0.z, a0.w);
        *(uint2*)(h1 + (size_t)row_a * 32 + c4) = p;
    }
    if (row_b < N_NODES) {
        uint2 p; p.x = f2h2(a1.x, a1.y); p.y = f2h2(a1.z, a1.w);
        *(uint2*)(h1 + (size_t)row_b * 32 + c4) = p;
    }
    float sa0 = a0.x * attss[c4] + a0.y * attss[c4 + 1]
              + a0.z * attss[c4 + 2] + a0.w * attss[c4 + 3];
    float sd0 = a0.x * attds[c4] + a0.y * attds[c4 + 1]
              + a0.z * attds[c4 + 2] + a0.w * attds[c4 + 3];
    float sa1 = a1.x * attss[c4] + a1.y * attss[c4 + 1]
              + a1.z * attss[c4 + 2] + a1.w * attss[c4 + 3];
    float sd1 = a1.x * attds[c4] + a1.y * attds[c4 + 1]
              + a1.z * attds[c4 + 2] + a1.w * attds[c4 + 3];
    sa0 += __shfl_xor(sa0, 1); sa0 += __shfl_xor(sa0, 2);
    sd0 += __shfl_xor(sd0, 1); sd0 += __shfl_xor(sd0, 2);
    sa1 += __shfl_xor(sa1, 1); sa1 += __shfl_xor(sa1, 2);
    sd1 += __shfl_xor(sd1, 1); sd1 += __shfl_xor(sd1, 2);
    const int head = colq >> 2;
    if ((colq & 3) == 0) {
        if (row_a < N_NODES) {
            a_src1[row_a * 2 + head] = sa0;
            a_dst1[row_a * 2 + head] = sd0;
        }
        if (row_b < N_NODES) {
            a_src1[row_b * 2 + head] = sa1;
            a_dst1[row_b * 2 + head] = sd1;
        }
    }
}

// -------- Layer-1 aggregation: deferred norm + 8-way unroll, fp16 h1 gathers --------
__global__ __launch_bounds__(256) void k_agg1(
    const int* __restrict__ cnt, const int* __restrict__ csr_src,
    const float* __restrict__ a_src1, const float* __restrict__ a_dst1,
    const __half* __restrict__ h1, float* __restrict__ out1)
{
    const int wid = (blockIdx.x * 256 + threadIdx.x) >> 6;
    const int lane = threadIdx.x & 63;
    if (wid >= N_NODES) return;
    const int len = min(cnt[(size_t)wid * CNT_PAD], CAP);
    const int beg = wid << 7, end = beg + len;
    const float2 ad = *(const float2*)(a_dst1 + 2 * (size_t)wid);
    const int slot = lane >> 5, ch = lane & 31;
    const int head = ch >> 4;
    const float adh = head ? ad.y : ad.x;
    const int rep = ((ch & 15) == 0);
    float acc = 0.f, sw = 0.f;
    int i = beg + slot;
    for (; i + 14 < end; i += 16) {
        int s[8]; float a[8], h[8], w[8];
        #pragma unroll
        for (int j = 0; j < 8; ++j) s[j] = csr_src[i + 2 * j];
        #pragma unroll
        for (int j = 0; j < 8; ++j) a[j] = a_src1[2 * (size_t)s[j] + head];
        #pragma unroll
        for (int j = 0; j < 8; ++j) h[j] = __half2float(h1[(size_t)s[j] * 32 + ch]);
        #pragma unroll
        for (int j = 0; j < 8; ++j) w[j] = __expf(lrelu(a[j] + adh));
        float wsum = 0.f;
        #pragma unroll
        for (int j = 0; j < 8; ++j) { wsum += w[j]; acc += w[j] * h[j]; }
        if (rep) sw += wsum;
    }
    for (; i < end; i += 2) {
        const int s = csr_src[i];
        const float w = __expf(lrelu(a_src1[2 * (size_t)s + head] + adh));
        if (rep) sw += w;
        acc += w * __half2float(h1[(size_t)s * 32 + ch]);
    }
    sw += __shfl_xor(sw, 32);
    const float swh = __shfl(sw, head << 4);
    acc += __shfl_xor(acc, 32);
    const float inv = 1.f / (swh + EPS_F);
    if (lane < 32) out1[(size_t)wid * 32 + lane] = acc * inv;
}

// ---------------- Kernel 4: h2 = elu(out1+b1) @ W2 ; a_src2/a_dst2 fused ----------------
__global__ __launch_bounds__(256) void k4_layer2(
    const float* __restrict__ out1, const float* __restrict__ b1,
    const float* __restrict__ W2, const float* __restrict__ att_src2,
    const float* __restrict__ att_dst2,
    float* __restrict__ h2, float* __restrict__ a_src2, float* __restrict__ a_dst2)
{
    __shared__ float act[16][32];
    __shared__ float w2s[32 * 16];
    __shared__ float b1s[32], as2[16], ad2[16];
    const int t = threadIdx.x;
    for (int i = t; i < 512; i += 256) w2s[i] = W2[i];
    if (t < 32) b1s[t] = b1[t];
    if (t < 16) { as2[t] = att_src2[t]; ad2[t] = att_dst2[t]; }
    __syncthreads();
    const int node0 = blockIdx.x * 16;
    for (int i = t; i < 512; i += 256) {
        const int nl = i >> 5, k = i & 31;
        const int row = node0 + nl;
        float v = 0.f;
        if (row < N_NODES) {
            v = out1[(size_t)row * 32 + k] + b1s[k];
            v = v > 0.f ? v : expm1f(v);
        }
        act[nl][k] = v;
    }
    __syncthreads();
    const int nl = t >> 4, j = t & 15;
    const int row = node0 + nl;
    float acc = 0.f;
    #pragma unroll
    for (int k = 0; k < 32; ++k) acc += act[nl][k] * w2s[k * 16 + j];
    if (row < N_NODES) h2[(size_t)row * 16 + j] = acc;
    float sa = acc * as2[j], sd = acc * ad2[j];
    #pragma unroll
    for (int m = 1; m < 16; m <<= 1) { sa += __shfl_xor(sa, m); sd += __shfl_xor(sd, m); }
    if (j == 0 && row < N_NODES) { a_src2[row] = sa; a_dst2[row] = sd; }
}

// -------- Layer-2 aggregation: deferred norm + 8-way MLP unroll --------
__global__ __launch_bounds__(256) void k_agg2(
    const int* __restrict__ cnt, const int* __restrict__ csr_src,
    const float* __restrict__ a_src2, const float* __restrict__ a_dst2,
    const float* __restrict__ h2, float* __restrict__ out2)
{
    const int wid = (blockIdx.x * 256 + threadIdx.x) >> 6;
    const int lane = threadIdx.x & 63;
    if (wid >= N_NODES) return;
    const int len = min(cnt[(size_t)wid * CNT_PAD], CAP);
    const int beg = wid << 7, end = beg + len;
    const float ad = a_dst2[wid];
    const int slot = lane >> 4, ch = lane & 15;
    const int rep = (ch == 0);
    float acc = 0.f, sw = 0.f;
    int i = beg + slot;
    for (; i + 28 < end; i += 32) {
        int s[8]; float a[8], h[8], w[8];
        #pragma unroll
        for (int j = 0; j < 8; ++j) s[j] = csr_src[i + 4 * j];
        #pragma unroll
        for (int j = 0; j < 8; ++j) a[j] = a_src2[s[j]];
        #pragma unroll
        for (int j = 0; j < 8; ++j) h[j] = h2[(size_t)s[j] * 16 + ch];
        #pragma unroll
        for (int j = 0; j < 8; ++j) w[j] = __expf(lrelu(a[j] + ad));
        float wsum = 0.f;
        #pragma unroll
        for (int j = 0; j < 8; ++j) { wsum += w[j]; acc += w[j] * h[j]; }
        if (rep) sw += wsum;
    }
    for (; i < end; i += 4) {
        const int s = csr_src[i];
        const float w = __expf(lrelu(a_src2[s] + ad));
        if (rep) sw += w;
        acc += w * h2[(size_t)s * 16 + ch];
    }
    #pragma unroll
    for (int m = 1; m < 64; m <<= 1) sw += __shfl_xor(sw, m);
    acc += __shfl_xor(acc, 16);
    acc += __shfl_xor(acc, 32);
    const float inv = 1.f / (sw + EPS_F);
    if (lane < 16) out2[(size_t)wid * 16 + lane] = acc * inv;
}

// -------- k_prep: hoist edge-MLP first layer to nodes (fp16 u/v) --------
__global__ __launch_bounds__(256) void k_prep(
    const float* __restrict__ out2, const float* __restrict__ b2,
    const float* __restrict__ Wm1, const float* __restrict__ bm1,
    __half* __restrict__ u, __half* __restrict__ v)
{
    __shared__ float wa[16 * 16], wb[16 * 16];
    __shared__ float act[16][17];
    __shared__ float b2s[16], bm1s[16];
    const int t = threadIdx.x;
    if (t < 256) {
        const int k = t >> 4, j = t & 15;
        wa[t] = Wm1[k * 16 + j];
        wb[t] = Wm1[(16 + k) * 16 + j];
    }
    if (t < 16) { b2s[t] = b2[t]; bm1s[t] = bm1[t]; }
    __syncthreads();
    const int node0 = blockIdx.x * 16;
    const int nl = t >> 4, c = t & 15;
    const int row = node0 + nl;
    act[nl][c] = (row < N_NODES) ? out2[(size_t)row * 16 + c] + b2s[c] : 0.f;
    __syncthreads();
    float su = bm1s[c], sv = 0.f;
    #pragma unroll
    for (int k = 0; k < 16; ++k) {
        const float a = act[nl][k];
        su += a * wa[k * 16 + c];
        sv += a * wb[k * 16 + c];
    }
    if (row < N_NODES) {
        u[(size_t)row * 16 + c] = __float2half(su);
        v[(size_t)row * 16 + c] = __float2half(sv);
    }
}

// ---------------- Kernel 7 lite: per-edge tail of the MLP (fp16 gathers) ----------------
__global__ __launch_bounds__(256) void k7_lite(
    const int* __restrict__ ei, const int* __restrict__ flag,
    const __half* __restrict__ u, const __half* __restrict__ v,
    const float* __restrict__ Wm2, const float* __restrict__ bm2,
    float* __restrict__ out)
{
    __shared__ float wm2s[16];
    __shared__ float bm2s;
    const int t = threadIdx.x;
    if (t < 16) wm2s[t] = Wm2[t];
    if (t == 0) bm2s = bm2[0];
    __syncthreads();
    const int e = blockIdx.x * 256 + t;
    if (e >= N_EDGES) return;
    const int f = flag[0];
    const int s = ld_src(ei, f, e);
    const int d = ld_dst(ei, f, e);
    const uint4* up = (const uint4*)(u + (size_t)s * 16);
    const uint4* vp = (const uint4*)(v + (size_t)d * 16);
    const uint4 ua = up[0], ub = up[1];
    const uint4 va = vp[0], vb = vp[1];
    float fl = bm2s;
    unsigned int uw[8] = {ua.x, ua.y, ua.z, ua.w, ub.x, ub.y, ub.z, ub.w};
    unsigned int vw[8] = {va.x, va.y, va.z, va.w, vb.x, vb.y, vb.z, vb.w};
    #pragma unroll
    for (int i = 0; i < 8; ++i) {
        const float2 a = h2f(uw[i]);
        const float2 b = h2f(vw[i]);
        fl += fmaxf(a.x + b.x, 0.f) * wm2s[2 * i];
        fl += fmaxf(a.y + b.y, 0.f) * wm2s[2 * i + 1];
    }
    out[e] = fmaxf(fl, 0.f);
}

extern "C" void kernel_launch(void* const* d_in, const int* in_sizes, int n_in,
                              void* d_out, int out_size, void* d_ws, size_t ws_size,
                              hipStream_t stream)
{
    const float* x        = (const float*)d_in[0];
    const int*   ei       = (const int*)d_in[1];
    const float* W1       = (const float*)d_in[2];
    const float* att_src1 = (const float*)d_in[3];
    const float* att_dst1 = (const float*)d_in[4];
    const float* b1       = (const float*)d_in[5];
    const float* W2       = (const float*)d_in[6];
    const float* att_src2 = (const float*)d_in[7];
    const float* att_dst2 = (const float*)d_in[8];
    const float* b2       = (const float*)d_in[9];
    const float* Wm1      = (const float*)d_in[10];
    const float* bm1      = (const float*)d_in[11];
    const float* Wm2      = (const float*)d_in[12];
    const float* bm2      = (const float*)d_in[13];

    float* ws = (float*)d_ws;
    size_t off = 0;
    __half* h1 = (__half*)(ws + off); off += 16 * (size_t)N_NODES;
    float* a_src1 = ws + off; off += 2  * (size_t)N_NODES;
    float* a_dst1 = ws + off; off += 2  * (size_t)N_NODES;
    float* out1   = ws + off; off += 32 * (size_t)N_NODES;
    float* h2     = ws + off; off += 16 * (size_t)N_NODES;
    float* a_src2 = ws + off; off += 1  * (size_t)N_NODES;
    float* a_dst2 = ws + off; off += 1  * (size_t)N_NODES;
    float* out2   = ws + off; off += 16 * (size_t)N_NODES;
    __half* u = (__half*)(ws + off); off += 8 * (size_t)N_NODES;
    __half* v = (__half*)(ws + off); off += 8 * (size_t)N_NODES;
    int* cnt     = (int*)(ws + off); off += (size_t)N_NODES * CNT_PAD;
    int* csr_src = (int*)(ws + off); off += (size_t)N_NODES * CAP;
    int* gcnt    = (int*)(ws + off); off += 256;
    int* flag    = (int*)(ws + off); off += 64;
    // bseg (16.06 MB) overlays the h1..out2 region: dead before k1_gemm1 runs.
    int2* bseg = (int2*)ws;

    k0_detect<<<1, 256, 0, stream>>>(ei, flag, gcnt);
    k_part<<<(N_EDGES + PCHUNK - 1) / PCHUNK, 1024, 0, stream>>>(ei, flag, gcnt, bseg);
    k_sub<<<NBK, 1024, 0, stream>>>(gcnt, bseg, cnt, csr_src);

    k1_gemm1<<<(N_NODES + 63) / 64, 256, 0, stream>>>(
        x, W1, att_src1, att_dst1, h1, a_src1, a_dst1);
    k_agg1<<<(N_NODES + 3) / 4, 256, 0, stream>>>(
        cnt, csr_src, a_src1, a_dst1, h1, out1);
    k4_layer2<<<(N_NODES + 15) / 16, 256, 0, stream>>>(
        out1, b1, W2, att_src2, att_dst2, h2, a_src2, a_dst2);
    k_agg2<<<(N_NODES + 3) / 4, 256, 0, stream>>>(
        cnt, csr_src, a_src2, a_dst2, h2, out2);
    k_prep<<<(N_NODES + 15) / 16, 256, 0, stream>>>(
        out2, b2, Wm1, bm1, u, v);
    k7_lite<<<(N_EDGES + 255) / 256, 256, 0, stream>>>(
        ei, flag, u, v, Wm2, bm2, (float*)d_out);
}